// Round 2
// baseline (675.011 us; speedup 1.0000x reference)
//
#include <hip/hip_runtime.h>

typedef unsigned short u16;
typedef float f32x4 __attribute__((ext_vector_type(4)));
typedef unsigned int uint4v __attribute__((ext_vector_type(4)));

#define TT 2048
#define THEAD 2046
#define DD 1024
#define PP 512
#define NSA 32
#define NSB 16

#define LGKM0 asm volatile("s_waitcnt lgkmcnt(0)" ::: "memory")
#define VMC(n) asm volatile("s_waitcnt vmcnt(" #n ")" ::: "memory")
#define SB0 __builtin_amdgcn_sched_barrier(0)
#define BAR __builtin_amdgcn_s_barrier()

// ---------- helpers ----------
__device__ __forceinline__ u16 f2bf(float f) {
  unsigned int u = __float_as_uint(f);
  return (u16)((u + 0x7fffu + ((u >> 16) & 1u)) >> 16);
}
__device__ __forceinline__ float bf2f(u16 h) {
  return __uint_as_float(((unsigned int)h) << 16);
}
__device__ __forceinline__ float tanh_fast(float x) {
  float cx = fminf(fmaxf(x, -15.f), 15.f);
  float e = __expf(2.f * cx);
  return (e - 1.f) * __builtin_amdgcn_rcpf(e + 1.f);
}
__device__ __forceinline__ void cp16(const void* g, void* l) {
  __builtin_amdgcn_global_load_lds(
      (const __attribute__((address_space(1))) unsigned int*)g,
      (__attribute__((address_space(3))) unsigned int*)l, 16, 0, 0);
}
__device__ __forceinline__ void mfma16(f32x4& c, uint4v a, uint4v b) {
  asm("v_mfma_f32_16x16x32_bf16 %0, %1, %2, %0" : "+v"(c) : "v"(a), "v"(b));
}
// Ct swizzle: element index for logical (row r, col p). Bijective within
// each 64-elem window; makes stride-1024B row reads 2-way (free).
__device__ __forceinline__ int ct_idx(int r, int p) {
  return (r << 9) + (p ^ ((r & 7) << 3));
}
// stage one BK=32 weight slab (512 rows x 32 k, 64B rows, linear) via 4 cp16/wave
__device__ __forceinline__ void stageW(const u16* __restrict__ wT, int K,
                                       u16* dst, int k0, int wid, int lane) {
  const int rb = (wid << 6) + (lane >> 2);
  const int kc = (lane & 3) << 3;
#pragma unroll
  for (int i = 0; i < 4; ++i)
    cp16(wT + (size_t)(rb + (i << 4)) * K + k0 + kc,
         dst + (((wid << 6) + (i << 4)) << 5));
}
__device__ __forceinline__ void at_write(u16* At, float4 v, int r_st, int kq) {
  uint2 pk;
  pk.x = (unsigned)f2bf(v.x) | ((unsigned)f2bf(v.y) << 16);
  pk.y = (unsigned)f2bf(v.z) | ((unsigned)f2bf(v.w) << 16);
  *(uint2*)&At[(r_st << 5) + (kq << 2)] = pk;
}

// ---------- kernel 1: transpose+convert weights to bf16 ----------
__global__ __launch_bounds__(256) void cvt_k(const float* __restrict__ ph,
                                             const float* __restrict__ hw,
                                             u16* __restrict__ phT,
                                             u16* __restrict__ w0T,
                                             u16* __restrict__ w1T) {
  __shared__ float tl[32][33];
  const int bid = blockIdx.x, tid = threadIdx.x;
  const float* src;
  u16* dst;
  int SC, SR, r0, c0;
  if (bid < 512) {
    int tr = bid >> 4, tc = bid & 15;
    src = ph; SC = 512; dst = phT; SR = 1024; r0 = tr * 32; c0 = tc * 32;
  } else if (bid < 768) {
    int i = bid - 512; int tr = i >> 4, tc = i & 15;
    src = hw; SC = 512; dst = w0T; SR = 512; r0 = tr * 32; c0 = tc * 32;
  } else {
    int i = bid - 768; int tr = i >> 4, tc = i & 15;
    src = hw + 512 * 512; SC = 512; dst = w1T; SR = 512; r0 = tr * 32; c0 = tc * 32;
  }
  for (int i = tid; i < 1024; i += 256) {
    int r = i >> 5, c = i & 31;
    tl[r][c] = src[(size_t)(r0 + r) * SC + c0 + c];
  }
  __syncthreads();
  for (int i = tid; i < 1024; i += 256) {
    int r = i >> 5, c = i & 31;
    dst[(size_t)(c0 + r) * SR + r0 + c] = f2bf(tl[c][r]);
  }
}

// ---------- kernel 2: fp32 bias ----------
__global__ __launch_bounds__(256) void bias_k(const float* __restrict__ x,
                                              const float* __restrict__ pp,
                                              const float* __restrict__ pc,
                                              float* __restrict__ bias) {
  const int b = blockIdx.x >> 3, pt = blockIdx.x & 7, tid = threadIdx.x;
  __shared__ float sprep[DD], schild[DD];
  __shared__ float red[4][64];
  for (int i = tid; i < DD; i += 256) {
    sprep[i] = x[((size_t)b * TT + (TT - 2)) * DD + i];
    schild[i] = x[((size_t)b * TT + (TT - 1)) * DD + i];
  }
  __syncthreads();
  const int pl = tid & 63, kq = tid >> 6;
  const int p = pt * 64 + pl;
  float s = 0.f;
  for (int k = kq * 256; k < kq * 256 + 256; ++k)
    s += sprep[k] * pp[(size_t)k * PP + p] + schild[k] * pc[(size_t)k * PP + p];
  red[kq][pl] = s;
  __syncthreads();
  if (tid < 64)
    bias[(size_t)b * PP + pt * 64 + tid] =
        red[0][tid] + red[1][tid] + red[2][tid] + red[3][tid];
}

// ---------- kernel 3: fused main (2-phase counted-vmcnt pipeline) ----------
__global__ __launch_bounds__(512, 2) void fused_main(
    const float* __restrict__ x, const u16* __restrict__ phT,
    const u16* __restrict__ w0T, const u16* __restrict__ w1T,
    const float* __restrict__ bias, const float* __restrict__ scorer,
    const int* __restrict__ mask, float* __restrict__ out,
    float* __restrict__ partials) {
  __shared__ u16 BtL[2][PP * 32];   // 2 x 32 KB weight slabs
  __shared__ u16 AtL[2][64 * 32];   // 2 x 4 KB X slabs
  __shared__ u16 Ct[64 * 512];      // 64 KB, XOR-swizzled
  __shared__ float ssc[PP];
  __shared__ float sred[64];

  const int tile = blockIdx.x, b = blockIdx.y;
  const int tid = threadIdx.x;
  const int lane = tid & 63, wid = tid >> 6;   // 8 waves, 1x8 grid: wave=64x64
  const int lr = lane & 15, kg = lane >> 4;

  ssc[tid] = scorer[tid];

  f32x4 acc[4][4];
#pragma unroll
  for (int mr = 0; mr < 4; ++mr)
#pragma unroll
    for (int nr = 0; nr < 4; ++nr) acc[mr][nr] = (f32x4){0.f, 0.f, 0.f, 0.f};

  const int r_st = tid >> 3, kq = tid & 7;
  const size_t xrow = ((size_t)b * TT + tile * 64 + r_st) * DD;

  // ---- stage A prologue ----
  float4 x0 = *(const float4*)(x + xrow + (kq << 2));
  float4 xa = *(const float4*)(x + xrow + 32 + (kq << 2));  // data for step 1
  float4 xb;
  stageW(phT, DD, &BtL[0][0], 0, wid, lane);
  VMC(0); SB0;
  at_write(&AtL[0][0], x0, r_st, kq);
  LGKM0; SB0;
  BAR;

#define STEP_A(KS, XCUR, XNXT)                                                 \
  {                                                                            \
    const int cur = (KS) & 1;                                                  \
    const int rem = NSA - 1 - (KS);                                            \
    if (rem > 0) stageW(phT, DD, &BtL[cur ^ 1][0], ((KS) + 1) << 5, wid, lane);\
    SB0;                                                                       \
    if (rem > 1)                                                               \
      XNXT = *(const float4*)(x + xrow + (((KS) + 2) << 5) + (kq << 2));       \
    SB0;                                                                       \
    if (rem > 0) {                                                             \
      if ((KS) > 0) {                                                          \
        if (rem > 1) { VMC(5); } else { VMC(4); }                              \
        SB0;                                                                   \
      }                                                                        \
      at_write(&AtL[cur ^ 1][0], XCUR, r_st, kq);                              \
    }                                                                          \
    uint4v af[4], bfr[4];                                                      \
    _Pragma("unroll") for (int mr = 0; mr < 4; ++mr)                           \
        af[mr] = *(const uint4v*)&AtL[cur][(((mr << 4) + lr) << 5) + (kg << 3)];\
    _Pragma("unroll") for (int nr = 0; nr < 4; ++nr)                           \
        bfr[nr] = *(const uint4v*)                                             \
            &BtL[cur][(((wid << 6) + (nr << 4) + lr) << 5) + (kg << 3)];       \
    LGKM0; SB0;                                                                \
    __builtin_amdgcn_s_setprio(1);                                             \
    _Pragma("unroll") for (int mr = 0; mr < 4; ++mr)                           \
        _Pragma("unroll") for (int nr = 0; nr < 4; ++nr)                       \
            mfma16(acc[mr][nr], af[mr], bfr[nr]);                              \
    __builtin_amdgcn_s_setprio(0);                                             \
    SB0;                                                                       \
    if (rem > 1) { VMC(1); } else { VMC(0); }                                  \
    SB0;                                                                       \
    BAR;                                                                       \
  }

  for (int ks2 = 0; ks2 < NSA; ks2 += 2) {
    STEP_A(ks2, xa, xb);
    STEP_A(ks2 + 1, xb, xa);
  }

  // ---- epilogue A: prefetch layer0 slab, then bias+tanh -> Ct ----
  stageW(w0T, PP, &BtL[0][0], 0, wid, lane);
  {
    float bv[4];
#pragma unroll
    for (int nr = 0; nr < 4; ++nr)
      bv[nr] = bias[(b << 9) + (wid << 6) + (nr << 4) + lr];
#pragma unroll
    for (int mr = 0; mr < 4; ++mr)
#pragma unroll
      for (int nr = 0; nr < 4; ++nr) {
        const int c = (wid << 6) + (nr << 4) + lr;
        const int r0 = (mr << 4) + (kg << 2);
#pragma unroll
        for (int j = 0; j < 4; ++j)
          Ct[ct_idx(r0 + j, c)] = f2bf(tanh_fast(acc[mr][nr][j] + bv[nr]));
      }
  }
  __syncthreads();  // drains the w0T cp16s too

  // ---- stages B and C ----
#define STEP_B(KS, WT)                                                         \
  {                                                                            \
    const int cur = (KS) & 1;                                                  \
    if ((KS) + 1 < NSB)                                                        \
      stageW(WT, PP, &BtL[cur ^ 1][0], ((KS) + 1) << 5, wid, lane);            \
    uint4v af[4], bfr[4];                                                      \
    _Pragma("unroll") for (int mr = 0; mr < 4; ++mr)                           \
        af[mr] = *(const uint4v*)                                              \
            &Ct[ct_idx((mr << 4) + lr, ((KS) << 5) + (kg << 3))];              \
    _Pragma("unroll") for (int nr = 0; nr < 4; ++nr)                           \
        bfr[nr] = *(const uint4v*)                                             \
            &BtL[cur][(((wid << 6) + (nr << 4) + lr) << 5) + (kg << 3)];       \
    LGKM0; SB0;                                                                \
    __builtin_amdgcn_s_setprio(1);                                             \
    _Pragma("unroll") for (int mr = 0; mr < 4; ++mr)                           \
        _Pragma("unroll") for (int nr = 0; nr < 4; ++nr)                       \
            mfma16(acc[mr][nr], af[mr], bfr[nr]);                              \
    __builtin_amdgcn_s_setprio(0);                                             \
    SB0;                                                                       \
    VMC(0); SB0;                                                               \
    BAR;                                                                       \
  }

  for (int layer = 0; layer < 2; ++layer) {
    const u16* wT = layer ? w1T : w0T;
#pragma unroll
    for (int mr = 0; mr < 4; ++mr)
#pragma unroll
      for (int nr = 0; nr < 4; ++nr) acc[mr][nr] = (f32x4){0.f, 0.f, 0.f, 0.f};
    for (int ks = 0; ks < NSB; ++ks) STEP_B(ks, wT);
    if (layer == 0) stageW(w1T, PP, &BtL[0][0], 0, wid, lane);
#pragma unroll
    for (int mr = 0; mr < 4; ++mr)
#pragma unroll
      for (int nr = 0; nr < 4; ++nr) {
        const int c = (wid << 6) + (nr << 4) + lr;
        const int r0 = (mr << 4) + (kg << 2);
#pragma unroll
        for (int j = 0; j < 4; ++j)
          Ct[ct_idx(r0 + j, c)] = f2bf(tanh_fast(acc[mr][nr][j]));
      }
    __syncthreads();
  }

  // ---- stage D: scores -> exp -> mask -> out, block partial sum ----
  {
    const int r = tid >> 3, j = tid & 7;
    const int p0 = j << 6;
    float s = 0.f;
#pragma unroll
    for (int i = 0; i < 8; ++i) {
      uint4v v = *(const uint4v*)&Ct[ct_idx(r, p0 + (i << 3))];
      const float* sc = &ssc[p0 + (i << 3)];
#pragma unroll
      for (int e = 0; e < 4; ++e) {
        unsigned int u = v[e];
        s += bf2f((u16)(u & 0xffffu)) * sc[e * 2] +
             bf2f((u16)(u >> 16)) * sc[e * 2 + 1];
      }
    }
    s += __shfl_down(s, 4, 8);
    s += __shfl_down(s, 2, 8);
    s += __shfl_down(s, 1, 8);
    if (j == 0) {
      const int tg = (tile << 6) + r;
      float e = 0.f;
      if (tg < THEAD && mask[(size_t)b * TT + tg] != 0) e = __expf(s);
      if (tg < THEAD) out[(size_t)b * THEAD + tg] = e;
      sred[r] = e;
    }
    __syncthreads();
    if (tid < 64) {
      float v = sred[tid];
      v += __shfl_down(v, 32);
      v += __shfl_down(v, 16);
      v += __shfl_down(v, 8);
      v += __shfl_down(v, 4);
      v += __shfl_down(v, 2);
      v += __shfl_down(v, 1);
      if (tid == 0) partials[(b << 5) + tile] = v;
    }
  }
}

// ---------- kernel 4: normalize ----------
__global__ __launch_bounds__(256) void norm_k(float* __restrict__ out,
                                              const float* __restrict__ partials) {
  const int b = blockIdx.y, j = blockIdx.x, tid = threadIdx.x;
  __shared__ float sinv;
  if (tid < 32) {
    float v = partials[(b << 5) + tid];
    v += __shfl_down(v, 16, 32);
    v += __shfl_down(v, 8, 32);
    v += __shfl_down(v, 4, 32);
    v += __shfl_down(v, 2, 32);
    v += __shfl_down(v, 1, 32);
    if (tid == 0) sinv = 1.f / (v + 1e-7f);
  }
  __syncthreads();
  const int t = (j << 8) + tid;
  if (t < THEAD) out[(size_t)b * THEAD + t] *= sinv;
}

extern "C" void kernel_launch(void* const* d_in, const int* in_sizes, int n_in,
                              void* d_out, int out_size, void* d_ws, size_t ws_size,
                              hipStream_t stream) {
  const float* x  = (const float*)d_in[0];
  const float* ph = (const float*)d_in[1];
  const float* pp = (const float*)d_in[2];
  const float* pc = (const float*)d_in[3];
  const float* hw = (const float*)d_in[4];
  const float* sc = (const float*)d_in[5];
  const int* mask = (const int*)d_in[6];
  float* out = (float*)d_out;

  char* ws = (char*)d_ws;
  u16* phT = (u16*)ws;
  u16* w0T = (u16*)(ws + (1 << 20));
  u16* w1T = (u16*)(ws + (1 << 20) + (1 << 19));
  float* biasb = (float*)(ws + (1 << 21));
  float* partials = (float*)(ws + (1 << 21) + 131072);

  cvt_k<<<1024, 256, 0, stream>>>(ph, hw, phT, w0T, w1T);
  bias_k<<<512, 256, 0, stream>>>(x, pp, pc, biasb);
  fused_main<<<dim3(32, 64), 512, 0, stream>>>(x, phT, w0T, w1T, biasb, sc,
                                               mask, out, partials);
  norm_k<<<dim3(8, 64), 256, 0, stream>>>(out, partials);
}

// Round 3
// 437.632 us; speedup vs baseline: 1.5424x; 1.5424x over previous
//
#include <hip/hip_runtime.h>

typedef unsigned short u16;
typedef float f32x4 __attribute__((ext_vector_type(4)));
typedef unsigned int uint4v __attribute__((ext_vector_type(4)));

#define TT 2048
#define THEAD 2046
#define DD 1024
#define PP 512

#define LGKM0 asm volatile("s_waitcnt lgkmcnt(0)" ::: "memory")
#define VMC(n) asm volatile("s_waitcnt vmcnt(" #n ")" ::: "memory")
#define SB0 __builtin_amdgcn_sched_barrier(0)
#define BAR __builtin_amdgcn_s_barrier()

// ---------- helpers ----------
__device__ __forceinline__ u16 f2bf(float f) {
  unsigned int u = __float_as_uint(f);
  return (u16)((u + 0x7fffu + ((u >> 16) & 1u)) >> 16);
}
__device__ __forceinline__ float bf2f(u16 h) {
  return __uint_as_float(((unsigned int)h) << 16);
}
__device__ __forceinline__ float tanh_fast(float x) {
  float cx = fminf(fmaxf(x, -15.f), 15.f);
  float e = __expf(2.f * cx);
  return (e - 1.f) * __builtin_amdgcn_rcpf(e + 1.f);
}
__device__ __forceinline__ void cp16(const void* g, void* l) {
  __builtin_amdgcn_global_load_lds(
      (const __attribute__((address_space(1))) unsigned int*)g,
      (__attribute__((address_space(3))) unsigned int*)l, 16, 0, 0);
}
__device__ __forceinline__ void mfma16(f32x4& c, uint4v a, uint4v b) {
  asm("v_mfma_f32_16x16x32_bf16 %0, %1, %2, %0" : "+v"(c) : "v"(a), "v"(b));
}
// Ct swizzle (bijective in 64-elem windows): conflict-free b128 row reads.
__device__ __forceinline__ int ct_idx(int r, int p) {
  return (r << 9) + (p ^ ((r & 7) << 3));
}
// Stage this wave's private 64x64 (bf16) slab region: 8 cp16, linear LDS dest,
// pre-swizzled global source col so reads can XOR-deswizzle (m173 pattern).
// src must be pre-offset to the wave's first row; dst to the wave's region.
__device__ __forceinline__ void stageW(const u16* __restrict__ src, int K,
                                       u16* dst, int k0, int lane) {
  const int rlo = lane >> 3;                       // row within 8-row group
  const int scol = (((lane & 7) ^ rlo) << 3) + k0; // swizzled 8-elem chunk
#pragma unroll
  for (int i = 0; i < 8; ++i)
    cp16(src + (size_t)((i << 3) + rlo) * K + scol, dst + (i << 9));
}
// X tile write: thread covers 8 floats -> one swizzled uint4 in At.
__device__ __forceinline__ void at_write(u16* At, float4 v0, float4 v1,
                                         int r_st, int kp) {
  uint4 pk;
  pk.x = (unsigned)f2bf(v0.x) | ((unsigned)f2bf(v0.y) << 16);
  pk.y = (unsigned)f2bf(v0.z) | ((unsigned)f2bf(v0.w) << 16);
  pk.z = (unsigned)f2bf(v1.x) | ((unsigned)f2bf(v1.y) << 16);
  pk.w = (unsigned)f2bf(v1.z) | ((unsigned)f2bf(v1.w) << 16);
  *(uint4*)((char*)At + (r_st << 7) + ((kp ^ (r_st & 7)) << 4)) = pk;
}

// ---------- kernel 1: transpose+convert weights to bf16 ----------
__global__ __launch_bounds__(256) void cvt_k(const float* __restrict__ ph,
                                             const float* __restrict__ hw,
                                             u16* __restrict__ phT,
                                             u16* __restrict__ w0T,
                                             u16* __restrict__ w1T) {
  __shared__ float tl[32][33];
  const int bid = blockIdx.x, tid = threadIdx.x;
  const float* src;
  u16* dst;
  int SC, SR, r0, c0;
  if (bid < 512) {
    int tr = bid >> 4, tc = bid & 15;
    src = ph; SC = 512; dst = phT; SR = 1024; r0 = tr * 32; c0 = tc * 32;
  } else if (bid < 768) {
    int i = bid - 512; int tr = i >> 4, tc = i & 15;
    src = hw; SC = 512; dst = w0T; SR = 512; r0 = tr * 32; c0 = tc * 32;
  } else {
    int i = bid - 768; int tr = i >> 4, tc = i & 15;
    src = hw + 512 * 512; SC = 512; dst = w1T; SR = 512; r0 = tr * 32; c0 = tc * 32;
  }
  for (int i = tid; i < 1024; i += 256) {
    int r = i >> 5, c = i & 31;
    tl[r][c] = src[(size_t)(r0 + r) * SC + c0 + c];
  }
  __syncthreads();
  for (int i = tid; i < 1024; i += 256) {
    int r = i >> 5, c = i & 31;
    dst[(size_t)(c0 + r) * SR + r0 + c] = f2bf(tl[c][r]);
  }
}

// ---------- kernel 2: fp32 bias ----------
__global__ __launch_bounds__(256) void bias_k(const float* __restrict__ x,
                                              const float* __restrict__ pp,
                                              const float* __restrict__ pc,
                                              float* __restrict__ bias) {
  const int b = blockIdx.x >> 3, pt = blockIdx.x & 7, tid = threadIdx.x;
  __shared__ float sprep[DD], schild[DD];
  __shared__ float red[4][64];
  for (int i = tid; i < DD; i += 256) {
    sprep[i] = x[((size_t)b * TT + (TT - 2)) * DD + i];
    schild[i] = x[((size_t)b * TT + (TT - 1)) * DD + i];
  }
  __syncthreads();
  const int pl = tid & 63, kq = tid >> 6;
  const int p = pt * 64 + pl;
  float s = 0.f;
  for (int k = kq * 256; k < kq * 256 + 256; ++k)
    s += sprep[k] * pp[(size_t)k * PP + p] + schild[k] * pc[(size_t)k * PP + p];
  red[kq][pl] = s;
  __syncthreads();
  if (tid < 64)
    bias[(size_t)b * PP + pt * 64 + tid] =
        red[0][tid] + red[1][tid] + red[2][tid] + red[3][tid];
}

// ---------- kernel 3: fused main ----------
// 1x8 wave grid: wave = all 64 rows x private 64-col strip. Weight slab is
// wave-private (stage+read by owner only) -> no barriers in hidden layers.
// Stage A: shared X tile double-buffered, 1 barrier/step, counted vmcnt.
__global__ __launch_bounds__(512) void fused_main(
    const float* __restrict__ x, const u16* __restrict__ phT,
    const u16* __restrict__ w0T, const u16* __restrict__ w1T,
    const float* __restrict__ bias, const float* __restrict__ scorer,
    const int* __restrict__ mask, float* __restrict__ out,
    float* __restrict__ partials) {
  __shared__ u16 Bt[PP * 64];      // 64 KB: 8 wave-private 64x64 regions
  __shared__ u16 AtL[2][64 * 64];  // 2 x 8 KB X tile (dbuf, swizzled)
  __shared__ u16 Ct[64 * 512];     // 64 KB composed tile (ct_idx swizzle)
  __shared__ float ssc[PP];
  __shared__ float sred[64];

  const int tile = blockIdx.x, b = blockIdx.y;
  const int tid = threadIdx.x;
  const int lane = tid & 63, wid = tid >> 6;
  const int lr = lane & 15, kg = lane >> 4;

  const u16* phTw = phT + ((size_t)(wid << 6)) * DD;
  const u16* w0Tw = w0T + ((size_t)(wid << 6)) * PP;
  const u16* w1Tw = w1T + ((size_t)(wid << 6)) * PP;
  u16* BtW = Bt + (wid << 12);

  f32x4 acc[4][4];
#pragma unroll
  for (int mr = 0; mr < 4; ++mr)
#pragma unroll
    for (int nr = 0; nr < 4; ++nr) acc[mr][nr] = (f32x4){0.f, 0.f, 0.f, 0.f};

  const int r_st = tid >> 3, kp = tid & 7;
  const float* xptr = x + ((size_t)b * TT + tile * 64 + r_st) * DD + (kp << 3);

  // ---- prologue ----
  ssc[tid] = scorer[tid];
  float bv[4];
#pragma unroll
  for (int nr = 0; nr < 4; ++nr)
    bv[nr] = bias[(b << 9) + (wid << 6) + (nr << 4) + lr];
  float4 x00 = *(const float4*)(xptr);
  float4 x01 = *(const float4*)(xptr + 4);
  VMC(0);
  at_write(AtL[0], x00, x01, r_st, kp);
  stageW(phTw, DD, BtW, 0, lane);
  SB0;
  float4 xa0 = *(const float4*)(xptr + 64);
  float4 xa1 = *(const float4*)(xptr + 68);
  float4 xb0, xb1;
  LGKM0;
  // fall into step 0 (VMC(2): 8 cp16 wait, 2 x-loads stay in flight)

#define ASTEP(K, XC0, XC1, XN0, XN1)                                           \
  {                                                                            \
    if ((K) < 15) { VMC(2); } else { VMC(0); }                                 \
    BAR;                                                                       \
    uint4v bfr0[4], bfr1[4], af0[4], af1[4];                                   \
    _Pragma("unroll") for (int nr = 0; nr < 4; ++nr) {                         \
      const int nl = (nr << 4) + lr;                                           \
      const char* bp = (const char*)BtW + (nl << 7);                           \
      bfr0[nr] = *(const uint4v*)(bp + ((kg << 4) ^ ((nl & 7) << 4)));         \
      bfr1[nr] = *(const uint4v*)(bp + ((64 + (kg << 4)) ^ ((nl & 7) << 4)));  \
    }                                                                          \
    _Pragma("unroll") for (int mr = 0; mr < 4; ++mr) {                         \
      const int r = (mr << 4) + lr;                                            \
      const char* ap = (const char*)AtL[(K) & 1] + (r << 7);                   \
      af0[mr] = *(const uint4v*)(ap + ((kg << 4) ^ ((r & 7) << 4)));           \
      af1[mr] = *(const uint4v*)(ap + ((64 + (kg << 4)) ^ ((r & 7) << 4)));    \
    }                                                                          \
    LGKM0;                                                                     \
    if ((K) < 15) stageW(phTw, DD, BtW, ((K) + 1) << 6, lane);                 \
    else          stageW(w0Tw, PP, BtW, 0, lane);                              \
    if ((K) < 15) at_write(AtL[((K) & 1) ^ 1], XC0, XC1, r_st, kp);            \
    SB0;                                                                       \
    if ((K) < 14) {                                                            \
      XN0 = *(const float4*)(xptr + (((K) + 2) << 6));                         \
      XN1 = *(const float4*)(xptr + (((K) + 2) << 6) + 4);                     \
    }                                                                          \
    __builtin_amdgcn_s_setprio(1);                                             \
    _Pragma("unroll") for (int mr = 0; mr < 4; ++mr)                           \
      _Pragma("unroll") for (int nr = 0; nr < 4; ++nr)                         \
        mfma16(acc[mr][nr], af0[mr], bfr0[nr]);                                \
    _Pragma("unroll") for (int mr = 0; mr < 4; ++mr)                           \
      _Pragma("unroll") for (int nr = 0; nr < 4; ++nr)                         \
        mfma16(acc[mr][nr], af1[mr], bfr1[nr]);                                \
    __builtin_amdgcn_s_setprio(0);                                             \
    LGKM0;                                                                     \
  }

#pragma unroll
  for (int kk = 0; kk < 8; ++kk) {
    ASTEP(2 * kk, xa0, xa1, xb0, xb1);
    ASTEP(2 * kk + 1, xb0, xb1, xa0, xa1);
  }

  // ---- epilogue A: bias + tanh -> Ct (Ct not yet read by anyone) ----
#pragma unroll
  for (int mr = 0; mr < 4; ++mr)
#pragma unroll
    for (int nr = 0; nr < 4; ++nr) {
      const int c = (wid << 6) + (nr << 4) + lr;
      const int r0 = (mr << 4) + (kg << 2);
#pragma unroll
      for (int j = 0; j < 4; ++j)
        Ct[ct_idx(r0 + j, c)] = f2bf(tanh_fast(acc[mr][nr][j] + bv[nr]));
    }
  LGKM0;
  BAR;

  // ---- hidden layers: barrier-free K-loops (wave-private slab) ----
#define BSTEP(K, CURW, NXTW, DONEXT)                                           \
  {                                                                            \
    VMC(0);                                                                    \
    uint4v bfr0[4], bfr1[4], af0[4], af1[4];                                   \
    _Pragma("unroll") for (int nr = 0; nr < 4; ++nr) {                         \
      const int nl = (nr << 4) + lr;                                           \
      const char* bp = (const char*)BtW + (nl << 7);                           \
      bfr0[nr] = *(const uint4v*)(bp + ((kg << 4) ^ ((nl & 7) << 4)));         \
      bfr1[nr] = *(const uint4v*)(bp + ((64 + (kg << 4)) ^ ((nl & 7) << 4)));  \
    }                                                                          \
    _Pragma("unroll") for (int mr = 0; mr < 4; ++mr) {                         \
      const int r = (mr << 4) + lr;                                            \
      af0[mr] = *(const uint4v*)&Ct[ct_idx(r, ((K) << 6) + (kg << 3))];        \
      af1[mr] = *(const uint4v*)&Ct[ct_idx(r, ((K) << 6) + 32 + (kg << 3))];   \
    }                                                                          \
    LGKM0;                                                                     \
    if ((K) < 7)       stageW(CURW, PP, BtW, ((K) + 1) << 6, lane);            \
    else if (DONEXT)   stageW(NXTW, PP, BtW, 0, lane);                         \
    __builtin_amdgcn_s_setprio(1);                                             \
    _Pragma("unroll") for (int mr = 0; mr < 4; ++mr)                           \
      _Pragma("unroll") for (int nr = 0; nr < 4; ++nr)                         \
        mfma16(acc[mr][nr], af0[mr], bfr0[nr]);                                \
    _Pragma("unroll") for (int mr = 0; mr < 4; ++mr)                           \
      _Pragma("unroll") for (int nr = 0; nr < 4; ++nr)                         \
        mfma16(acc[mr][nr], af1[mr], bfr1[nr]);                                \
    __builtin_amdgcn_s_setprio(0);                                             \
  }

#pragma unroll
  for (int mr = 0; mr < 4; ++mr)
#pragma unroll
    for (int nr = 0; nr < 4; ++nr) acc[mr][nr] = (f32x4){0.f, 0.f, 0.f, 0.f};
#pragma unroll
  for (int k = 0; k < 8; ++k) BSTEP(k, w0Tw, w1Tw, true);
  BAR;  // all waves done reading Ct (layer-0 inputs)
#pragma unroll
  for (int mr = 0; mr < 4; ++mr)
#pragma unroll
    for (int nr = 0; nr < 4; ++nr) {
      const int c = (wid << 6) + (nr << 4) + lr;
      const int r0 = (mr << 4) + (kg << 2);
#pragma unroll
      for (int j = 0; j < 4; ++j)
        Ct[ct_idx(r0 + j, c)] = f2bf(tanh_fast(acc[mr][nr][j]));
    }
  LGKM0;
  BAR;

#pragma unroll
  for (int mr = 0; mr < 4; ++mr)
#pragma unroll
    for (int nr = 0; nr < 4; ++nr) acc[mr][nr] = (f32x4){0.f, 0.f, 0.f, 0.f};
#pragma unroll
  for (int k = 0; k < 8; ++k) BSTEP(k, w1Tw, w1Tw, false);
  BAR;
#pragma unroll
  for (int mr = 0; mr < 4; ++mr)
#pragma unroll
    for (int nr = 0; nr < 4; ++nr) {
      const int c = (wid << 6) + (nr << 4) + lr;
      const int r0 = (mr << 4) + (kg << 2);
#pragma unroll
      for (int j = 0; j < 4; ++j)
        Ct[ct_idx(r0 + j, c)] = f2bf(tanh_fast(acc[mr][nr][j]));
    }
  __syncthreads();

  // ---- stage D: scores -> exp -> mask -> out, block partial sum ----
  {
    const int r = tid >> 3, j = tid & 7;
    const int p0 = j << 6;
    float s = 0.f;
#pragma unroll
    for (int i = 0; i < 8; ++i) {
      uint4v v = *(const uint4v*)&Ct[ct_idx(r, p0 + (i << 3))];
      const float* sc = &ssc[p0 + (i << 3)];
#pragma unroll
      for (int e = 0; e < 4; ++e) {
        unsigned int u = v[e];
        s += bf2f((u16)(u & 0xffffu)) * sc[e * 2] +
             bf2f((u16)(u >> 16)) * sc[e * 2 + 1];
      }
    }
    s += __shfl_down(s, 4, 8);
    s += __shfl_down(s, 2, 8);
    s += __shfl_down(s, 1, 8);
    if (j == 0) {
      const int tg = (tile << 6) + r;
      float e = 0.f;
      if (tg < THEAD && mask[(size_t)b * TT + tg] != 0) e = __expf(s);
      if (tg < THEAD) out[(size_t)b * THEAD + tg] = e;
      sred[r] = e;
    }
    __syncthreads();
    if (tid < 64) {
      float v = sred[tid];
      v += __shfl_down(v, 32);
      v += __shfl_down(v, 16);
      v += __shfl_down(v, 8);
      v += __shfl_down(v, 4);
      v += __shfl_down(v, 2);
      v += __shfl_down(v, 1);
      if (tid == 0) partials[(b << 5) + tile] = v;
    }
  }
}

// ---------- kernel 4: normalize ----------
__global__ __launch_bounds__(256) void norm_k(float* __restrict__ out,
                                              const float* __restrict__ partials) {
  const int b = blockIdx.y, j = blockIdx.x, tid = threadIdx.x;
  __shared__ float sinv;
  if (tid < 32) {
    float v = partials[(b << 5) + tid];
    v += __shfl_down(v, 16, 32);
    v += __shfl_down(v, 8, 32);
    v += __shfl_down(v, 4, 32);
    v += __shfl_down(v, 2, 32);
    v += __shfl_down(v, 1, 32);
    if (tid == 0) sinv = 1.f / (v + 1e-7f);
  }
  __syncthreads();
  const int t = (j << 8) + tid;
  if (t < THEAD) out[(size_t)b * THEAD + t] *= sinv;
}

extern "C" void kernel_launch(void* const* d_in, const int* in_sizes, int n_in,
                              void* d_out, int out_size, void* d_ws, size_t ws_size,
                              hipStream_t stream) {
  const float* x  = (const float*)d_in[0];
  const float* ph = (const float*)d_in[1];
  const float* pp = (const float*)d_in[2];
  const float* pc = (const float*)d_in[3];
  const float* hw = (const float*)d_in[4];
  const float* sc = (const float*)d_in[5];
  const int* mask = (const int*)d_in[6];
  float* out = (float*)d_out;

  char* ws = (char*)d_ws;
  u16* phT = (u16*)ws;
  u16* w0T = (u16*)(ws + (1 << 20));
  u16* w1T = (u16*)(ws + (1 << 20) + (1 << 19));
  float* biasb = (float*)(ws + (1 << 21));
  float* partials = (float*)(ws + (1 << 21) + 131072);

  cvt_k<<<1024, 256, 0, stream>>>(ph, hw, phT, w0T, w1T);
  bias_k<<<512, 256, 0, stream>>>(x, pp, pc, biasb);
  fused_main<<<dim3(32, 64), 512, 0, stream>>>(x, phT, w0T, w1T, biasb, sc,
                                               mask, out, partials);
  norm_k<<<dim3(8, 64), 256, 0, stream>>>(out, partials);
}